// Round 10
// baseline (875.863 us; speedup 1.0000x reference)
//
#include <hip/hip_runtime.h>
#include <hip/hip_bf16.h>
#include <stdint.h>

// Problem: B=64, T=128, F=16, H=512, S=2.  All inputs fp32, lengths int32, out fp32 [64][14].
//
// R1: fixed half-staged h_l (NaN). R2: 1338us. R3: relaxed poll -> 831us (lstmk 635).
// R4: per-wave RELEASE flags -> regressed 1450us. R5: poll-on-data sentinel -> 656us (lstmk 465).
// R6: coalesced poll -> 612us (lstmk 405). R7: decaying poll -> regressed (detect must stay hot).
// R8: 64x512 topology -> regressed (spin concentration). R9: dense transactions -> neutral
//     (lstmk 400, 3.13us/step). Protocol tweaks exhausted -> floor is MALL round-trip physics.
// R10: XCD-LOCAL FAST PATH, mapping-independent:
//   - producer stores h to BOTH h_fast (plain store -> own XCD L2, write-back) and h_hist
//     (agent store -> MALL, as before).
//   - consumer polls h_fast with sc0 (L1-bypass, L2-hit) asm global_load_dwordx4 for <=10
//     sweeps: same-XCD producers visible at ~200-300cy L2 RT instead of ~700cy MALL RT.
//     Row-group blocks are bid≡rr (mod 8) -> likely co-resident on one XCD (round-robin
//     dispatch heuristic). If words stay sentinel (cross-XCD producer: its dirty L2 line is
//     invisible here), FALL BACK to the R9 agent/MALL loop -> correctness never depends on
//     the workgroup->XCD mapping. Total-failure cost ~= R9 baseline.
//   - h_fast (128 slots x 128KB = 16.78MB) reuses the temb buffer (dead after gemmB);
//     prep2 moved after gemmB and sentinel-fills it.
//
// Reshape quirk (faithful to torch): segment s', step t' uses source timestep n_t=(s'*128+t')>>1
// and embedding branch n_s=(s'*128+t')&1.

typedef __attribute__((ext_vector_type(8))) short bf16x8_t;
typedef __attribute__((ext_vector_type(4))) float f32x4_t;
typedef __attribute__((ext_vector_type(4))) unsigned int u32x4_t;

#define SENT 0xAAAAAAAAu
#define FAST_TRIES 10

// ---------------- workspace layout (bytes) ----------------
#define OFF_G      0u                      // bf16 [8192][2048]   33,554,432
#define OFF_TEMB   33554432u               // bf16 [8192][1024]   16,777,216  (reused as h_fast)
#define OFF_HH     50331648u               // bf16 [129][8rr][16cg][16row][32u] 16,908,288
#define OFF_WHH    67239936u               // bf16 [2048][512]     2,097,152
#define OFF_WMID   69337088u               // bf16 [2048][1024]    4,194,304
#define OFF_WC0    73531392u               // f32  [2048][8]          65,536
#define OFF_WC1    73596928u               // f32  [2048][8] (6 used) 65,536
#define OFF_BC     73662464u               // f32  [2][2048]          16,384
#define OFF_HFIN   73678848u               // f32  [64][1024]        262,144
// total ~74 MB

__device__ __forceinline__ float bf2f(uint16_t u){
  union { uint32_t i; float f; } v; v.i = ((uint32_t)u) << 16; return v.f;
}
__device__ __forceinline__ uint16_t f2b(float f){
  union { float f; uint32_t i; } v; v.f = f;
  uint32_t r = v.i + 0x7fffu + ((v.i >> 16) & 1u);  // RNE
  return (uint16_t)(r >> 16);
}
__device__ __forceinline__ float sigm(float x){ return 1.0f/(1.0f + __expf(-x)); }
__device__ __forceinline__ float tanh_(float x){
  float xc = fminf(fmaxf(x, -15.f), 15.f);
  float t = __expf(2.f*xc);
  return (t - 1.f)/(t + 1.f);
}

// ---------------- prep1: weight folding + bf16 casts ----------------
__global__ void prep1(const float* __restrict__ W_ih, const float* __restrict__ W_hh,
                      const float* __restrict__ W_is0, const float* __restrict__ b_is0,
                      const float* __restrict__ W_is1, const float* __restrict__ b_is1,
                      const float* __restrict__ b_ih, const float* __restrict__ b_hh,
                      uint16_t* __restrict__ whh_b, uint16_t* __restrict__ wmid_b,
                      float* __restrict__ wc0, float* __restrict__ wc1, float* __restrict__ bc){
  const int n = blockIdx.x;        // gate column 0..2047
  const int tid = threadIdx.x;     // 256
  __shared__ float wrow[512];
  wrow[tid]       = W_ih[(size_t)n*1536 + tid];
  wrow[tid + 256] = W_ih[(size_t)n*1536 + 256 + tid];
  for (int j = tid; j < 1024; j += 256)
    wmid_b[(size_t)n*1024 + j] = f2b(W_ih[(size_t)n*1536 + 512 + j]);
  for (int k = tid; k < 512; k += 256)
    whh_b[(size_t)n*512 + k] = f2b(W_hh[(size_t)n*512 + k]);
  __syncthreads();
  if (tid < 8){
    float s = 0.f;
    for (int k = 0; k < 512; ++k) s += wrow[k]*W_is0[k*8 + tid];
    wc0[n*8 + tid] = s;
  } else if (tid < 16){
    int c = tid - 8;
    float s = 0.f;
    if (c < 6){ for (int k = 0; k < 512; ++k) s += wrow[k]*W_is1[k*6 + c]; }
    wc1[n*8 + c] = s;              // c==6,7 stay 0 (stride-8 padding)
  } else if (tid == 16){
    float s = b_ih[n] + b_hh[n];
    for (int k = 0; k < 512; ++k) s += wrow[k]*b_is0[k];
    bc[n] = s;
  } else if (tid == 17){
    float s = b_ih[n] + b_hh[n];
    for (int k = 0; k < 512; ++k) s += wrow[k]*b_is1[k];
    bc[2048 + n] = s;
  }
}

// ------ prep2: h_hist[0]=h0 (region layout), h_hist[1..128]=SENT, h_fast[all]=SENT ------
// Runs AFTER gemmB (h_fast reuses the temb buffer).
__global__ void prep2(const float* __restrict__ h0, uint16_t* __restrict__ h_hist,
                      uint16_t* __restrict__ h_fast){
  int i = blockIdx.x*256 + threadIdx.x;   // grid 32896 -> 8,421,376 u32 words
  uint32_t* hh = (uint32_t*)h_hist;
  uint32_t* hf = (uint32_t*)h_fast;
  if (i < 32768){                          // level 0: [rr][cg16][row16][u32]
    int e    = i*2;                        // even element index
    int rrcg = e >> 9;                     // 512 elems per region
    int rr   = rrcg >> 4, cg = rrcg & 15;
    int rm   = e & 511;
    int row  = rm >> 5, u = rm & 31;
    int b    = (rr*16 + row) & 63;         // both segments start at h0[b]
    int unit = cg*32 + u;
    uint32_t lo = f2b(h0[(size_t)b*512 + unit]);
    uint32_t hi = f2b(h0[(size_t)b*512 + unit + 1]);
    uint32_t wd = lo | (hi << 16);
    if (wd == SENT) wd ^= 1u;              // can't happen (h0>=0) but cheap guard
    hh[i] = wd;
  } else if (i < 4227072){
    hh[i] = SENT;
  } else if (i < 8421376){
    hf[i - 4227072] = SENT;                // 128 fast slots x 32768 u32
  }
}

// ---------------- tembk: timestep embedding, bf16 ----------------
__global__ void tembk(const float* __restrict__ x, uint16_t* __restrict__ temb){
  const int rid = blockIdx.x;       // (b*128 + t)
  const int k = threadIdx.x;        // 0..255
  float x0 = x[(size_t)rid*16 + 0], x1 = x[(size_t)rid*16 + 1];
  float f = __expf((float)k * (-9.210340371976184f/256.f));  // 10000^(-k/256)
  float a0 = x0*f, a1 = x1*f;
  size_t base = (size_t)rid*1024;
  temb[base + k]        = f2b(__cosf(a0));
  temb[base + 256 + k]  = f2b(__sinf(a0));
  temb[base + 512 + k]  = f2b(__cosf(a1));
  temb[base + 768 + k]  = f2b(__sinf(a1));
}

// ---------------- gemmB: G = temb[8192,1024] @ wmid[2048,1024]^T  (bf16 MFMA) ----------------
__launch_bounds__(256)
__global__ void gemmB(const uint16_t* __restrict__ temb, const uint16_t* __restrict__ wmid,
                      uint16_t* __restrict__ G){
  __shared__ __align__(16) uint16_t Al[128][72];  // 64 + 8 pad
  __shared__ __align__(16) uint16_t Bl[128][72];
  const int tid = threadIdx.x;
  const int m0 = blockIdx.x*128, n0 = blockIdx.y*128;
  const int w = tid >> 6, lane = tid & 63;
  const int q = lane >> 4, ln = lane & 15;
  const int wm = w >> 1, wn = w & 1;
  const int srow = tid >> 1, shalf = tid & 1;

  f32x4_t acc[4][4];
  #pragma unroll
  for (int a = 0; a < 4; ++a)
    #pragma unroll
    for (int b = 0; b < 4; ++b) acc[a][b] = (f32x4_t){0.f,0.f,0.f,0.f};

  for (int kb = 0; kb < 16; ++kb){
    const uint4* ga = (const uint4*)(temb + (size_t)(m0 + srow)*1024 + kb*64 + shalf*32);
    const uint4* gb = (const uint4*)(wmid + (size_t)(n0 + srow)*1024 + kb*64 + shalf*32);
    uint4 va[4], vb[4];
    #pragma unroll
    for (int i = 0; i < 4; ++i){ va[i] = ga[i]; vb[i] = gb[i]; }
    #pragma unroll
    for (int i = 0; i < 4; ++i){
      *(uint4*)&Al[srow][shalf*32 + i*8] = va[i];
      *(uint4*)&Bl[srow][shalf*32 + i*8] = vb[i];
    }
    __syncthreads();
    #pragma unroll
    for (int kc = 0; kc < 2; ++kc){
      bf16x8_t af[4], bf[4];
      #pragma unroll
      for (int mt = 0; mt < 4; ++mt) af[mt] = *(const bf16x8_t*)&Al[wm*64 + mt*16 + ln][kc*32 + q*8];
      #pragma unroll
      for (int nt = 0; nt < 4; ++nt) bf[nt] = *(const bf16x8_t*)&Bl[wn*64 + nt*16 + ln][kc*32 + q*8];
      #pragma unroll
      for (int mt = 0; mt < 4; ++mt)
        #pragma unroll
        for (int nt = 0; nt < 4; ++nt)
          acc[mt][nt] = __builtin_amdgcn_mfma_f32_16x16x32_bf16(af[mt], bf[nt], acc[mt][nt], 0, 0, 0);
    }
    __syncthreads();
  }
  #pragma unroll
  for (int mt = 0; mt < 4; ++mt)
    #pragma unroll
    for (int nt = 0; nt < 4; ++nt)
      #pragma unroll
      for (int r = 0; r < 4; ++r){
        int Mr = m0 + wm*64 + mt*16 + q*4 + r;    // C/D: col=lane&15, row=quad*4+reg (m89-verified)
        int Nc = n0 + wn*64 + nt*16 + ln;
        G[(size_t)Mr*2048 + Nc] = f2b(acc[mt][nt][r]);
      }
}

// ---------------- lstmk: persistent recurrence (R10: XCD-local fast path) ----------------
// 128 blocks = 8 row-groups (16 rows) x 16 col-groups (32 units). blockIdx = g*8 + rr.
// h_hist/h_fast level layout: [rr][cg16][row16][u32] -- 1KB contiguous per block region.
// h_fast slot s holds level s+1 (128 slots); level 0 is slow-only (prefilled by prep2).
__launch_bounds__(256)
__global__ void lstmk(const float* __restrict__ x, const float* __restrict__ c0,
                      const int* __restrict__ lengths,
                      const uint16_t* __restrict__ whh_b, const uint16_t* __restrict__ G,
                      const float* __restrict__ wc0, const float* __restrict__ wc1,
                      const float* __restrict__ bc,
                      uint16_t* __restrict__ h_hist, uint16_t* __restrict__ h_fast,
                      float* __restrict__ hfin){
  __shared__ __align__(16) uint16_t h_l[2][16][552]; // cols 0..511 h, 512..519 xf, 520..543 zeros

  const int tid = threadIdx.x;
  const int bid = blockIdx.x;
  const int rr = bid & 7;         // row-group
  const int g  = bid >> 3;        // col-group
  const int k0 = g*32;
  const int sp = rr >> 2;         // segment of this row-group
  const int w = tid >> 6, lane = tid & 63;
  const int q = lane >> 4, ln = lane & 15;
  const int u8 = ln & 7, gh = ln >> 3;          // unit-in-octet, gate-half
  const int unit = k0 + w*8 + u8;               // this lane's hidden unit
  const int gl0 = gh*512 + unit;                // tile0 gate rows: i (gh=0), f (gh=1)
  const int gl1 = (2 + gh)*512 + unit;          // tile1 gate rows: g (gh=0), o (gh=1)

  const int LVL = 65536;                        // elems per level

  // W_hh B-fragments resident in registers, remapped N-tiles.
  bf16x8_t barr0[16], barr1[16];
  #pragma unroll
  for (int kc = 0; kc < 16; ++kc){
    barr0[kc] = *(const bf16x8_t*)(whh_b + (size_t)gl0*512 + kc*32 + q*8);
    barr1[kc] = *(const bf16x8_t*)(whh_b + (size_t)gl1*512 + kc*32 + q*8);
  }
  // K-extension B-fragments (xf @ Wc): rows k=512+q*8+j; only q==0 carries Wc, others zero.
  bf16x8_t e0f[2], e1f[2];
  #pragma unroll
  for (int nsI = 0; nsI < 2; ++nsI){
    bf16x8_t v0 = {0,0,0,0,0,0,0,0}, v1 = {0,0,0,0,0,0,0,0};
    if (q == 0){
      const float* wcs = nsI ? wc1 : wc0;
      #pragma unroll
      for (int jj = 0; jj < 8; ++jj){
        ((uint16_t*)&v0)[jj] = f2b(wcs[gl0*8 + jj]);
        ((uint16_t*)&v1)[jj] = f2b(wcs[gl1*8 + jj]);
      }
    }
    e0f[nsI] = v0; e1f[nsI] = v1;
  }
  // biases per lane (per ns)
  float bc0v[2] = { bc[gl0], bc[2048 + gl0] };
  float bc1v[2] = { bc[gl1], bc[2048 + gl1] };

  // per-lane row ownership (C-layout rows q*4+r), cell state for ln<8 lanes
  int   bmr[4], lenr[4];
  float cst[4];
  #pragma unroll
  for (int r = 0; r < 4; ++r){
    int row = rr*16 + q*4 + r;
    bmr[r]  = row & 63;
    lenr[r] = lengths[bmr[r]];
    cst[r]  = c0[(size_t)bmr[r]*512 + unit];
  }

  // Poll map (lane-dense): wave w polls regions w*4..w*4+3; lane covers 16B at lane*16
  // within each region -> each load instruction's 64 lanes span 1KB contiguous.
  const int prow = lane >> 2;          // 0..15 row within region
  const int pcol = (lane & 3)*8;       // elem col 0,8,16,24 (16B chunk)
  // xf staging map (tid<128): (row xm, col xc)
  const int xm = tid >> 3, xc = tid & 7;
  const int xb = (rr*16 + xm) & 63;

  // own-region store base (elems, level-relative)
  const size_t stb = ((size_t)rr*8192 + g*512);

  // zero the K-extension tail (cols 520..543), both buffers
  for (int idx = tid; idx < 2*16*32; idx += 256)
    h_l[idx >> 9][(idx >> 5) & 15][520 + (idx & 31)] = 0;

  for (int t = 0; t < 128; ++t){
    const int qidx = sp*128 + t;
    const int ntm = qidx >> 1;     // source timestep (reshape interleave)
    const int ns  = qidx & 1;      // embedding branch
    const int buf = t & 1;

    // --- early independent loads: G slice (C-layout, cached) + xf source ---
    uint16_t g0r[4], g1r[4];
    #pragma unroll
    for (int r = 0; r < 4; ++r){
      size_t grow = (size_t)(bmr[r]*128 + ntm)*2048;
      g0r[r] = G[grow + gl0];
      g1r[r] = G[grow + gl1];
    }
    float xv = 0.f;
    if (tid < 128){
      if (ns == 0)      xv = x[(size_t)(xb*128 + ntm)*16 + 2 + xc];
      else if (xc < 6)  xv = x[(size_t)(xb*128 + ntm)*16 + 10 + xc];
    }

    // --- exchange: XCD-local fast path (sc0/L2) with MALL fallback ---
    u32x4_t hv4[4];
    bool got = false;
    if (t > 0){
      const uint16_t* fl = h_fast + (size_t)(t-1)*LVL + (size_t)rr*8192;
      const u32x4_t* p0 = (const u32x4_t*)(fl + (size_t)(w*4 + 0)*512 + prow*32 + pcol);
      const u32x4_t* p1 = (const u32x4_t*)(fl + (size_t)(w*4 + 1)*512 + prow*32 + pcol);
      const u32x4_t* p2 = (const u32x4_t*)(fl + (size_t)(w*4 + 2)*512 + prow*32 + pcol);
      const u32x4_t* p3 = (const u32x4_t*)(fl + (size_t)(w*4 + 3)*512 + prow*32 + pcol);
      for (int it = 0; it < FAST_TRIES; ++it){
        u32x4_t a, b, c, d;
        asm volatile(
          "global_load_dwordx4 %0, %4, off sc0\n\t"
          "global_load_dwordx4 %1, %5, off sc0\n\t"
          "global_load_dwordx4 %2, %6, off sc0\n\t"
          "global_load_dwordx4 %3, %7, off sc0\n\t"
          "s_waitcnt vmcnt(0)"
          : "=&v"(a), "=&v"(b), "=&v"(c), "=&v"(d)
          : "v"(p0), "v"(p1), "v"(p2), "v"(p3)
          : "memory");
        hv4[0] = a; hv4[1] = b; hv4[2] = c; hv4[3] = d;
        bool ok = true;
        #pragma unroll
        for (int i = 0; i < 4; ++i)
          #pragma unroll
          for (int jx = 0; jx < 4; ++jx)
            ok &= (hv4[i][jx] != SENT);
        if (__all(ok)){ got = true; break; }
        __builtin_amdgcn_s_sleep(1);
      }
    }
    if (!got){
      // slow path: agent/MALL poll (always correct; level prefilled for t==0)
      const unsigned long long* lvl = (const unsigned long long*)
          (h_hist + (size_t)t*LVL + (size_t)rr*8192);
      while (true){
        bool ok = true;
        #pragma unroll
        for (int i = 0; i < 4; ++i){
          const unsigned long long* p = lvl + ((size_t)(w*4 + i)*128 + prow*8 + (pcol >> 2));
          unsigned long long a = __hip_atomic_load(&p[0], __ATOMIC_RELAXED, __HIP_MEMORY_SCOPE_AGENT);
          unsigned long long b = __hip_atomic_load(&p[1], __ATOMIC_RELAXED, __HIP_MEMORY_SCOPE_AGENT);
          hv4[i][0] = (uint32_t)a; hv4[i][1] = (uint32_t)(a >> 32);
          hv4[i][2] = (uint32_t)b; hv4[i][3] = (uint32_t)(b >> 32);
          ok &= (hv4[i][0] != SENT) & (hv4[i][1] != SENT)
              & (hv4[i][2] != SENT) & (hv4[i][3] != SENT);
        }
        if (__all(ok)) break;
        __builtin_amdgcn_s_sleep(1);
      }
    }
    #pragma unroll
    for (int i = 0; i < 4; ++i){
      int reg = w*4 + i;
      *(u32x4_t*)&h_l[buf][prow][reg*32 + pcol] = hv4[i];
    }
    if (tid < 128) h_l[buf][xm][512 + xc] = f2b(xv);
    __syncthreads();   // the only barrier per step (stage -> MFMA read)

    // --- gates = G + bias + [h|xf] @ [Whh|Wc]^T  (17 kc chunks) ---
    f32x4_t acc0, acc1;
    {
      float b0 = ns ? bc0v[1] : bc0v[0];
      float b1 = ns ? bc1v[1] : bc1v[0];
      #pragma unroll
      for (int r = 0; r < 4; ++r){ acc0[r] = bf2f(g0r[r]) + b0; acc1[r] = bf2f(g1r[r]) + b1; }
    }
    #pragma unroll
    for (int kc = 0; kc < 16; ++kc){
      bf16x8_t a = *(const bf16x8_t*)&h_l[buf][ln][kc*32 + q*8];
      acc0 = __builtin_amdgcn_mfma_f32_16x16x32_bf16(a, barr0[kc], acc0, 0, 0, 0);
      acc1 = __builtin_amdgcn_mfma_f32_16x16x32_bf16(a, barr1[kc], acc1, 0, 0, 0);
    }
    {
      bf16x8_t a = *(const bf16x8_t*)&h_l[buf][ln][512 + q*8];
      acc0 = __builtin_amdgcn_mfma_f32_16x16x32_bf16(a, ns ? e0f[1] : e0f[0], acc0, 0, 0, 0);
      acc1 = __builtin_amdgcn_mfma_f32_16x16x32_bf16(a, ns ? e1f[1] : e1f[0], acc1, 0, 0, 0);
    }

    // --- register gate exchange: lane ln has (i,g) for gh=0, (f,o) for gh=1 ---
    float pf[4], po[4];
    #pragma unroll
    for (int r = 0; r < 4; ++r){
      pf[r] = __shfl_xor(acc0[r], 8);
      po[r] = __shfl_xor(acc1[r], 8);
    }
    if (ln < 8){
      uint32_t hb[4]; float hF[4];
      #pragma unroll
      for (int r = 0; r < 4; ++r){
        float ig = acc0[r], fg = pf[r], gg = acc1[r], og = po[r];
        cst[r] = sigm(fg)*cst[r] + sigm(ig)*tanh_(gg);
        float h = sigm(og)*tanh_(cst[r]);
        hF[r] = h; hb[r] = (uint32_t)f2b(h);
      }
      #pragma unroll
      for (int r = 0; r < 4; ++r){
        uint32_t ph = (uint32_t)__shfl_xor((int)hb[r], 1);
        uint32_t packed = hb[r] | (ph << 16);          // valid on even ln: units (u8,u8+1)
        if (packed == SENT) packed ^= 1u;              // 1-ulp-at-3e-13 guard
        uint32_t hi = (uint32_t)__shfl_xor((int)packed, 2);  // neighbor pair (u8+2,u8+3)
        if ((ln & 3) == 0){
          unsigned long long v = (unsigned long long)packed | ((unsigned long long)hi << 32);
          size_t eoff = stb + (size_t)(q*4 + r)*32 + w*8 + u8;
          // slow (MALL) store: always-correct path
          unsigned long long* hp = (unsigned long long*)(h_hist + (size_t)(t+1)*LVL + eoff);
          __hip_atomic_store(hp, v, __ATOMIC_RELAXED, __HIP_MEMORY_SCOPE_AGENT);
          // fast (own-XCD L2) store: plain write-back store, slot t holds level t+1
          unsigned long long* fp = (unsigned long long*)(h_fast + (size_t)t*LVL + eoff);
          __hip_atomic_store(fp, v, __ATOMIC_RELAXED, __HIP_MEMORY_SCOPE_WORKGROUP);
        }
        if (t == lenr[r] - 1)
          hfin[(size_t)bmr[r]*1024 + sp*512 + unit] = hF[r];
      }
    }
    // no flag, no drain: the data is the flag.
  }
}

// ---------------- outk: out = sigmoid(hfin @ W_o^T + b_o) ----------------
__global__ void outk(const float* __restrict__ hfin, const float* __restrict__ W_o,
                     const float* __restrict__ b_o, float* __restrict__ out){
  __shared__ float hl[1024];
  __shared__ float red[16][17];
  const int b = blockIdx.x, tid = threadIdx.x;
  #pragma unroll
  for (int i = 0; i < 4; ++i) hl[tid + i*256] = hfin[(size_t)b*1024 + tid + i*256];
  __syncthreads();
  const int o = tid >> 4, j0 = tid & 15;
  float s = 0.f;
  if (o < 14){
    for (int j = j0; j < 1024; j += 16) s += hl[j]*W_o[(size_t)o*1024 + j];
  }
  red[o][j0] = s;
  __syncthreads();
  if (tid < 14){
    float tot = b_o[tid];
    #pragma unroll
    for (int i = 0; i < 16; ++i) tot += red[tid][i];
    out[b*14 + tid] = 1.0f/(1.0f + __expf(-tot));
  }
}

extern "C" void kernel_launch(void* const* d_in, const int* in_sizes, int n_in,
                              void* d_out, int out_size, void* d_ws, size_t ws_size,
                              hipStream_t stream){
  const float* x     = (const float*)d_in[0];
  const int*   lens  = (const int*)  d_in[1];
  const float* h0    = (const float*)d_in[2];
  const float* c0    = (const float*)d_in[3];
  const float* W_is0 = (const float*)d_in[4];
  const float* b_is0 = (const float*)d_in[5];
  const float* W_is1 = (const float*)d_in[6];
  const float* b_is1 = (const float*)d_in[7];
  const float* W_ih  = (const float*)d_in[8];
  const float* W_hh  = (const float*)d_in[9];
  const float* b_ih  = (const float*)d_in[10];
  const float* b_hh  = (const float*)d_in[11];
  const float* W_o   = (const float*)d_in[12];
  const float* b_o   = (const float*)d_in[13];
  float* out = (float*)d_out;

  char* ws = (char*)d_ws;   // needs ~74 MB
  uint16_t* G      = (uint16_t*)(ws + OFF_G);
  uint16_t* temb   = (uint16_t*)(ws + OFF_TEMB);   // reused as h_fast after gemmB
  uint16_t* h_hist = (uint16_t*)(ws + OFF_HH);
  uint16_t* whh_b  = (uint16_t*)(ws + OFF_WHH);
  uint16_t* wmid_b = (uint16_t*)(ws + OFF_WMID);
  float* wc0  = (float*)(ws + OFF_WC0);
  float* wc1  = (float*)(ws + OFF_WC1);
  float* bc   = (float*)(ws + OFF_BC);
  float* hfin = (float*)(ws + OFF_HFIN);
  uint16_t* h_fast = temb;

  hipLaunchKernelGGL(prep1, dim3(2048), dim3(256), 0, stream,
                     W_ih, W_hh, W_is0, b_is0, W_is1, b_is1, b_ih, b_hh,
                     whh_b, wmid_b, wc0, wc1, bc);
  hipLaunchKernelGGL(tembk, dim3(8192), dim3(256), 0, stream, x, temb);
  hipLaunchKernelGGL(gemmB, dim3(64, 16), dim3(256), 0, stream, temb, wmid_b, G);
  hipLaunchKernelGGL(prep2, dim3(32896), dim3(256), 0, stream, h0, h_hist, h_fast);
  hipLaunchKernelGGL(lstmk, dim3(128), dim3(256), 0, stream,
                     x, c0, lens, whh_b, G, wc0, wc1, bc, h_hist, h_fast, hfin);
  hipLaunchKernelGGL(outk, dim3(64), dim3(256), 0, stream, hfin, W_o, b_o, out);
}

// Round 11
// 590.364 us; speedup vs baseline: 1.4836x; 1.4836x over previous
//
#include <hip/hip_runtime.h>
#include <hip/hip_bf16.h>
#include <stdint.h>

// Problem: B=64, T=128, F=16, H=512, S=2.  All inputs fp32, lengths int32, out fp32 [64][14].
//
// R1: fixed half-staged h_l (NaN). R2: 1338us. R3: relaxed poll -> 831us (lstmk 635).
// R4: per-wave RELEASE flags -> regressed 1450us. R5: poll-on-data sentinel -> 656us (lstmk 465).
// R6: coalesced poll -> 612us (lstmk 405). R7: decaying poll -> regressed (detect must stay hot).
// R8: 64x512 topology -> regressed (spin concentration). R9: dense transactions -> neutral
//     (lstmk 400, 3.13us/step) -- BEST for the recurrence; MALL-RT physics floor.
// R10: XCD-local sc0 fast path -> regressed 670us (fast path never hits: blocks not
//     co-resident / dirty remote L2 invisible; 10 failed tries/step + dual-store overhead).
// R11: lstmk reverted to R9-exact. Attack the OTHER ~200us instead:
//   - gemmB: m97-lever staging via __builtin_amdgcn_global_load_lds width=16 (unpadded LDS,
//     wave-uniform base + lane*16) + LDS-bounce vectorized epilogue (contiguous 128B/thread
//     uint4 stores instead of 64x scattered 2B stores). Expect ~130 -> ~55us.
//   - prep1: fold-dots parallelized (16 dots x 16 threads x 32-elem partials + LDS reduce).
//
// Reshape quirk (faithful to torch): segment s', step t' uses source timestep n_t=(s'*128+t')>>1
// and embedding branch n_s=(s'*128+t')&1.

typedef __attribute__((ext_vector_type(8))) short bf16x8_t;
typedef __attribute__((ext_vector_type(4))) float f32x4_t;

#define SENT 0xAAAAAAAAu

// ---------------- workspace layout (bytes) ----------------
#define OFF_G      0u                      // bf16 [8192][2048]   33,554,432
#define OFF_TEMB   33554432u               // bf16 [8192][1024]   16,777,216
#define OFF_HH     50331648u               // bf16 [129][8rr][16cg][16row][32u] 16,908,288
#define OFF_WHH    67239936u               // bf16 [2048][512]     2,097,152
#define OFF_WMID   69337088u               // bf16 [2048][1024]    4,194,304
#define OFF_WC0    73531392u               // f32  [2048][8]          65,536
#define OFF_WC1    73596928u               // f32  [2048][8] (6 used) 65,536
#define OFF_BC     73662464u               // f32  [2][2048]          16,384
#define OFF_HFIN   73678848u               // f32  [64][1024]        262,144
// total ~74 MB

__device__ __forceinline__ float bf2f(uint16_t u){
  union { uint32_t i; float f; } v; v.i = ((uint32_t)u) << 16; return v.f;
}
__device__ __forceinline__ uint16_t f2b(float f){
  union { float f; uint32_t i; } v; v.f = f;
  uint32_t r = v.i + 0x7fffu + ((v.i >> 16) & 1u);  // RNE
  return (uint16_t)(r >> 16);
}
__device__ __forceinline__ float sigm(float x){ return 1.0f/(1.0f + __expf(-x)); }
__device__ __forceinline__ float tanh_(float x){
  float xc = fminf(fmaxf(x, -15.f), 15.f);
  float t = __expf(2.f*xc);
  return (t - 1.f)/(t + 1.f);
}
// async global->LDS, 16B per lane; LDS dst = wave-uniform base + lane*16 (m97/m104)
__device__ __forceinline__ void gl_lds16(const void* g, void* l){
  __builtin_amdgcn_global_load_lds(
      (const __attribute__((address_space(1))) void*)g,
      (__attribute__((address_space(3))) void*)l, 16, 0, 0);
}

// ---------------- prep1: weight folding + bf16 casts ----------------
__global__ void prep1(const float* __restrict__ W_ih, const float* __restrict__ W_hh,
                      const float* __restrict__ W_is0, const float* __restrict__ b_is0,
                      const float* __restrict__ W_is1, const float* __restrict__ b_is1,
                      const float* __restrict__ b_ih, const float* __restrict__ b_hh,
                      uint16_t* __restrict__ whh_b, uint16_t* __restrict__ wmid_b,
                      float* __restrict__ wc0, float* __restrict__ wc1, float* __restrict__ bc){
  const int n = blockIdx.x;        // gate column 0..2047
  const int tid = threadIdx.x;     // 256
  __shared__ float wrow[512];
  __shared__ float red[16][17];
  wrow[tid]       = W_ih[(size_t)n*1536 + tid];
  wrow[tid + 256] = W_ih[(size_t)n*1536 + 256 + tid];
  for (int j = tid; j < 1024; j += 256)
    wmid_b[(size_t)n*1024 + j] = f2b(W_ih[(size_t)n*1536 + 512 + j]);
  for (int k = tid; k < 512; k += 256)
    whh_b[(size_t)n*512 + k] = f2b(W_hh[(size_t)n*512 + k]);
  __syncthreads();
  // 16 dots of length 512, each split over 16 threads x 32 elems
  {
    const int d = tid >> 4, jp = tid & 15;
    float s = 0.f;
    const int kk0 = jp*32;
    if (d < 8){
      for (int k = kk0; k < kk0 + 32; ++k) s += wrow[k]*W_is0[k*8 + d];
    } else if (d < 14){
      int c = d - 8;
      for (int k = kk0; k < kk0 + 32; ++k) s += wrow[k]*W_is1[k*6 + c];
    } else if (d == 14){
      for (int k = kk0; k < kk0 + 32; ++k) s += wrow[k]*b_is0[k];
    } else {
      for (int k = kk0; k < kk0 + 32; ++k) s += wrow[k]*b_is1[k];
    }
    red[d][jp] = s;
  }
  __syncthreads();
  if (tid < 16){
    float tot = 0.f;
    #pragma unroll
    for (int i = 0; i < 16; ++i) tot += red[tid][i];
    if (tid < 8)       wc0[n*8 + tid] = tot;
    else if (tid < 14) wc1[n*8 + (tid - 8)] = tot;
    else if (tid == 14) bc[n]        = b_ih[n] + b_hh[n] + tot;
    else                bc[2048 + n] = b_ih[n] + b_hh[n] + tot;
  } else if (tid == 16){
    wc1[n*8 + 6] = 0.f; wc1[n*8 + 7] = 0.f;   // stride-8 padding cols
  }
}

// ---------------- prep2: h_hist[0]=h0 (region layout), h_hist[1..128]=sentinel ------------
__global__ void prep2(const float* __restrict__ h0, uint16_t* __restrict__ h_hist){
  int i = blockIdx.x*256 + threadIdx.x;   // grid 16512 -> 4,227,072 u32 words
  uint32_t* hh = (uint32_t*)h_hist;
  if (i < 32768){                          // level 0: [rr][cg16][row16][u32]
    int e    = i*2;                        // even element index
    int rrcg = e >> 9;                     // 512 elems per region
    int rr   = rrcg >> 4, cg = rrcg & 15;
    int rm   = e & 511;
    int row  = rm >> 5, u = rm & 31;
    int b    = (rr*16 + row) & 63;         // both segments start at h0[b]
    int unit = cg*32 + u;
    uint32_t lo = f2b(h0[(size_t)b*512 + unit]);
    uint32_t hi = f2b(h0[(size_t)b*512 + unit + 1]);
    uint32_t wd = lo | (hi << 16);
    if (wd == SENT) wd ^= 1u;              // can't happen (h0>=0) but cheap guard
    hh[i] = wd;
  } else if (i < 4227072){
    hh[i] = SENT;
  }
}

// ---------------- tembk: timestep embedding, bf16 ----------------
__global__ void tembk(const float* __restrict__ x, uint16_t* __restrict__ temb){
  const int rid = blockIdx.x;       // (b*128 + t)
  const int k = threadIdx.x;        // 0..255
  float x0 = x[(size_t)rid*16 + 0], x1 = x[(size_t)rid*16 + 1];
  float f = __expf((float)k * (-9.210340371976184f/256.f));  // 10000^(-k/256)
  float a0 = x0*f, a1 = x1*f;
  size_t base = (size_t)rid*1024;
  temb[base + k]        = f2b(__cosf(a0));
  temb[base + 256 + k]  = f2b(__sinf(a0));
  temb[base + 512 + k]  = f2b(__cosf(a1));
  temb[base + 768 + k]  = f2b(__sinf(a1));
}

// ---------------- gemmB: G = temb[8192,1024] @ wmid[2048,1024]^T  (R11: m97-style) ----------
// BM=BN=128, BK=64, unpadded LDS, global_load_lds width=16 staging, LDS-bounce epilogue.
__launch_bounds__(256)
__global__ void gemmB(const uint16_t* __restrict__ temb, const uint16_t* __restrict__ wmid,
                      uint16_t* __restrict__ G){
  __shared__ __align__(16) uint16_t smem[16384];   // 32KB: Al[128][64] + Bl[128][64]; C bounce
  uint16_t* Al = smem;
  uint16_t* Bl = smem + 8192;
  const int tid = threadIdx.x;
  const int m0 = blockIdx.x*128, n0 = blockIdx.y*128;
  const int w = tid >> 6, lane = tid & 63;
  const int q = lane >> 4, ln = lane & 15;
  const int wm = w >> 1, wn = w & 1;
  // staging map: wave w, instr i covers rows w*32+i*8 .. +7 (1KB); lane -> row+(l>>3), col (l&7)*8
  const int srow_l = (lane >> 3);          // 0..7
  const int scol   = (lane & 7)*8;         // elem col within 64

  f32x4_t acc[4][4];
  #pragma unroll
  for (int a = 0; a < 4; ++a)
    #pragma unroll
    for (int b = 0; b < 4; ++b) acc[a][b] = (f32x4_t){0.f,0.f,0.f,0.f};

  for (int kb = 0; kb < 16; ++kb){
    #pragma unroll
    for (int i = 0; i < 4; ++i){
      int row0 = w*32 + i*8;
      int row  = row0 + srow_l;
      gl_lds16(temb + (size_t)(m0 + row)*1024 + kb*64 + scol, &Al[row0*64]);
      gl_lds16(wmid + (size_t)(n0 + row)*1024 + kb*64 + scol, &Bl[row0*64]);
    }
    __syncthreads();
    #pragma unroll
    for (int kc = 0; kc < 2; ++kc){
      bf16x8_t af[4], bf[4];
      #pragma unroll
      for (int mt = 0; mt < 4; ++mt)
        af[mt] = *(const bf16x8_t*)&Al[(wm*64 + mt*16 + ln)*64 + kc*32 + q*8];
      #pragma unroll
      for (int nt = 0; nt < 4; ++nt)
        bf[nt] = *(const bf16x8_t*)&Bl[(wn*64 + nt*16 + ln)*64 + kc*32 + q*8];
      #pragma unroll
      for (int mt = 0; mt < 4; ++mt)
        #pragma unroll
        for (int nt = 0; nt < 4; ++nt)
          acc[mt][nt] = __builtin_amdgcn_mfma_f32_16x16x32_bf16(af[mt], bf[nt], acc[mt][nt], 0, 0, 0);
    }
    __syncthreads();
  }

  // epilogue: bounce C through LDS (32KB), then contiguous 128B/thread vector stores
  #pragma unroll
  for (int mt = 0; mt < 4; ++mt)
    #pragma unroll
    for (int nt = 0; nt < 4; ++nt)
      #pragma unroll
      for (int r = 0; r < 4; ++r){
        int Mr = wm*64 + mt*16 + q*4 + r;    // C/D: col=lane&15, row=quad*4+reg (m89-verified)
        int Nc = wn*64 + nt*16 + ln;
        smem[Mr*128 + Nc] = f2b(acc[mt][nt][r]);
      }
  __syncthreads();
  {
    const int erow = tid >> 1, eh = tid & 1;
    uint4* gdst = (uint4*)(G + (size_t)(m0 + erow)*2048 + n0 + eh*64);
    const uint4* lsrc = (const uint4*)&smem[erow*128 + eh*64];
    #pragma unroll
    for (int i2 = 0; i2 < 8; ++i2) gdst[i2] = lsrc[i2];
  }
}

// ---------------- lstmk: persistent recurrence (R9-exact, best: 400us) ----------------
// 128 blocks = 8 row-groups (16 rows) x 16 col-groups (32 units). blockIdx = g*8 + rr.
// h_hist level layout: [rr][cg16][row16][u32] -- 1KB contiguous per block region.
__launch_bounds__(256)
__global__ void lstmk(const float* __restrict__ x, const float* __restrict__ c0,
                      const int* __restrict__ lengths,
                      const uint16_t* __restrict__ whh_b, const uint16_t* __restrict__ G,
                      const float* __restrict__ wc0, const float* __restrict__ wc1,
                      const float* __restrict__ bc,
                      uint16_t* __restrict__ h_hist, float* __restrict__ hfin){
  __shared__ __align__(16) uint16_t h_l[2][16][552]; // cols 0..511 h, 512..519 xf, 520..543 zeros

  const int tid = threadIdx.x;
  const int bid = blockIdx.x;
  const int rr = bid & 7;         // row-group
  const int g  = bid >> 3;        // col-group
  const int k0 = g*32;
  const int sp = rr >> 2;         // segment of this row-group
  const int w = tid >> 6, lane = tid & 63;
  const int q = lane >> 4, ln = lane & 15;
  const int u8 = ln & 7, gh = ln >> 3;          // unit-in-octet, gate-half
  const int unit = k0 + w*8 + u8;               // this lane's hidden unit
  const int gl0 = gh*512 + unit;                // tile0 gate rows: i (gh=0), f (gh=1)
  const int gl1 = (2 + gh)*512 + unit;          // tile1 gate rows: g (gh=0), o (gh=1)

  const int LVL = 65536;                        // elems per h_hist level

  // W_hh B-fragments resident in registers, remapped N-tiles.
  bf16x8_t barr0[16], barr1[16];
  #pragma unroll
  for (int kc = 0; kc < 16; ++kc){
    barr0[kc] = *(const bf16x8_t*)(whh_b + (size_t)gl0*512 + kc*32 + q*8);
    barr1[kc] = *(const bf16x8_t*)(whh_b + (size_t)gl1*512 + kc*32 + q*8);
  }
  // K-extension B-fragments (xf @ Wc): rows k=512+q*8+j; only q==0 carries Wc, others zero.
  bf16x8_t e0f[2], e1f[2];
  #pragma unroll
  for (int nsI = 0; nsI < 2; ++nsI){
    bf16x8_t v0 = {0,0,0,0,0,0,0,0}, v1 = {0,0,0,0,0,0,0,0};
    if (q == 0){
      const float* wcs = nsI ? wc1 : wc0;
      #pragma unroll
      for (int jj = 0; jj < 8; ++jj){
        ((uint16_t*)&v0)[jj] = f2b(wcs[gl0*8 + jj]);
        ((uint16_t*)&v1)[jj] = f2b(wcs[gl1*8 + jj]);
      }
    }
    e0f[nsI] = v0; e1f[nsI] = v1;
  }
  // biases per lane (per ns)
  float bc0v[2] = { bc[gl0], bc[2048 + gl0] };
  float bc1v[2] = { bc[gl1], bc[2048 + gl1] };

  // per-lane row ownership (C-layout rows q*4+r), cell state for ln<8 lanes
  int   bmr[4], lenr[4];
  float cst[4];
  #pragma unroll
  for (int r = 0; r < 4; ++r){
    int row = rr*16 + q*4 + r;
    bmr[r]  = row & 63;
    lenr[r] = lengths[bmr[r]];
    cst[r]  = c0[(size_t)bmr[r]*512 + unit];
  }

  // Poll map (lane-dense): wave w polls regions w*4..w*4+3; lane covers 16B at lane*16
  // within each region -> each load instruction's 64 lanes span 1KB contiguous.
  const int prow = lane >> 2;          // 0..15 row within region
  const int pcol = (lane & 3)*8;       // elem col 0,8,16,24 (16B chunk)
  // xf staging map (tid<128): (row xm, col xc)
  const int xm = tid >> 3, xc = tid & 7;
  const int xb = (rr*16 + xm) & 63;

  // own-region store base (u64 index), lanes ln%4==0 of the ln<8 group store 8B each
  const size_t stb = ((size_t)rr*8192 + g*512);   // elems, level-relative

  // zero the K-extension tail (cols 520..543), both buffers
  for (int idx = tid; idx < 2*16*32; idx += 256)
    h_l[idx >> 9][(idx >> 5) & 15][520 + (idx & 31)] = 0;

  for (int t = 0; t < 128; ++t){
    const int qidx = sp*128 + t;
    const int ntm = qidx >> 1;     // source timestep (reshape interleave)
    const int ns  = qidx & 1;      // embedding branch
    const int buf = t & 1;

    // --- early independent loads: G slice (C-layout, cached) + xf source ---
    uint16_t g0r[4], g1r[4];
    #pragma unroll
    for (int r = 0; r < 4; ++r){
      size_t grow = (size_t)(bmr[r]*128 + ntm)*2048;
      g0r[r] = G[grow + gl0];
      g1r[r] = G[grow + gl1];
    }
    float xv = 0.f;
    if (tid < 128){
      if (ns == 0)      xv = x[(size_t)(xb*128 + ntm)*16 + 2 + xc];
      else if (xc < 6)  xv = x[(size_t)(xb*128 + ntm)*16 + 10 + xc];
    }

    // --- hot poll-on-data, lane-dense: wave w sweeps its 4 regions (4KB) per iteration ---
    {
      const unsigned long long* lvl = (const unsigned long long*)h_hist
                                      + (((size_t)t*LVL + (size_t)rr*8192) >> 2);
      unsigned long long hv[4][2];
      while (true){
        bool ok = true;
        #pragma unroll
        for (int i = 0; i < 4; ++i){
          const unsigned long long* p = lvl + ((size_t)(w*4 + i)*128 + prow*8 + (pcol >> 2));
          hv[i][0] = __hip_atomic_load(&p[0], __ATOMIC_RELAXED, __HIP_MEMORY_SCOPE_AGENT);
          hv[i][1] = __hip_atomic_load(&p[1], __ATOMIC_RELAXED, __HIP_MEMORY_SCOPE_AGENT);
          ok &= ((uint32_t)hv[i][0] != SENT) & ((uint32_t)(hv[i][0] >> 32) != SENT)
              & ((uint32_t)hv[i][1] != SENT) & ((uint32_t)(hv[i][1] >> 32) != SENT);
        }
        if (__all(ok)) break;
        __builtin_amdgcn_s_sleep(1);
      }
      #pragma unroll
      for (int i = 0; i < 4; ++i){
        int reg = w*4 + i;
        *(unsigned long long*)&h_l[buf][prow][reg*32 + pcol]     = hv[i][0];
        *(unsigned long long*)&h_l[buf][prow][reg*32 + pcol + 4] = hv[i][1];
      }
    }
    if (tid < 128) h_l[buf][xm][512 + xc] = f2b(xv);
    __syncthreads();   // the only barrier per step (stage -> MFMA read)

    // --- gates = G + bias + [h|xf] @ [Whh|Wc]^T  (17 kc chunks) ---
    f32x4_t acc0, acc1;
    {
      float b0 = ns ? bc0v[1] : bc0v[0];
      float b1 = ns ? bc1v[1] : bc1v[0];
      #pragma unroll
      for (int r = 0; r < 4; ++r){ acc0[r] = bf2f(g0r[r]) + b0; acc1[r] = bf2f(g1r[r]) + b1; }
    }
    #pragma unroll
    for (int kc = 0; kc < 16; ++kc){
      bf16x8_t a = *(const bf16x8_t*)&h_l[buf][ln][kc*32 + q*8];
      acc0 = __builtin_amdgcn_mfma_f32_16x16x32_bf16(a, barr0[kc], acc0, 0, 0, 0);
      acc1 = __builtin_amdgcn_mfma_f32_16x16x32_bf16(a, barr1[kc], acc1, 0, 0, 0);
    }
    {
      bf16x8_t a = *(const bf16x8_t*)&h_l[buf][ln][512 + q*8];
      acc0 = __builtin_amdgcn_mfma_f32_16x16x32_bf16(a, ns ? e0f[1] : e0f[0], acc0, 0, 0, 0);
      acc1 = __builtin_amdgcn_mfma_f32_16x16x32_bf16(a, ns ? e1f[1] : e1f[0], acc1, 0, 0, 0);
    }

    // --- register gate exchange: lane ln has (i,g) for gh=0, (f,o) for gh=1 ---
    float pf[4], po[4];
    #pragma unroll
    for (int r = 0; r < 4; ++r){
      pf[r] = __shfl_xor(acc0[r], 8);
      po[r] = __shfl_xor(acc1[r], 8);
    }
    if (ln < 8){
      uint32_t hb[4]; float hF[4];
      #pragma unroll
      for (int r = 0; r < 4; ++r){
        float ig = acc0[r], fg = pf[r], gg = acc1[r], og = po[r];
        cst[r] = sigm(fg)*cst[r] + sigm(ig)*tanh_(gg);
        float h = sigm(og)*tanh_(cst[r]);
        hF[r] = h; hb[r] = (uint32_t)f2b(h);
      }
      #pragma unroll
      for (int r = 0; r < 4; ++r){
        uint32_t ph = (uint32_t)__shfl_xor((int)hb[r], 1);
        uint32_t packed = hb[r] | (ph << 16);          // valid on even ln: units (u8,u8+1)
        if (packed == SENT) packed ^= 1u;              // 1-ulp-at-3e-13 guard
        uint32_t hi = (uint32_t)__shfl_xor((int)packed, 2);  // neighbor pair (u8+2,u8+3)
        if ((ln & 3) == 0){
          unsigned long long v = (unsigned long long)packed | ((unsigned long long)hi << 32);
          unsigned long long* hp = (unsigned long long*)h_hist
              + (((size_t)(t+1)*LVL + stb + (size_t)(q*4 + r)*32 + w*8 + u8) >> 2);
          __hip_atomic_store(hp, v, __ATOMIC_RELAXED, __HIP_MEMORY_SCOPE_AGENT);
        }
        if (t == lenr[r] - 1)
          hfin[(size_t)bmr[r]*1024 + sp*512 + unit] = hF[r];
      }
    }
    // no flag, no drain: the data is the flag.
  }
}

// ---------------- outk: out = sigmoid(hfin @ W_o^T + b_o) ----------------
__global__ void outk(const float* __restrict__ hfin, const float* __restrict__ W_o,
                     const float* __restrict__ b_o, float* __restrict__ out){
  __shared__ float hl[1024];
  __shared__ float red[16][17];
  const int b = blockIdx.x, tid = threadIdx.x;
  #pragma unroll
  for (int i = 0; i < 4; ++i) hl[tid + i*256] = hfin[(size_t)b*1024 + tid + i*256];
  __syncthreads();
  const int o = tid >> 4, j0 = tid & 15;
  float s = 0.f;
  if (o < 14){
    for (int j = j0; j < 1024; j += 16) s += hl[j]*W_o[(size_t)o*1024 + j];
  }
  red[o][j0] = s;
  __syncthreads();
  if (tid < 14){
    float tot = b_o[tid];
    #pragma unroll
    for (int i = 0; i < 16; ++i) tot += red[tid][i];
    out[b*14 + tid] = 1.0f/(1.0f + __expf(-tot));
  }
}

extern "C" void kernel_launch(void* const* d_in, const int* in_sizes, int n_in,
                              void* d_out, int out_size, void* d_ws, size_t ws_size,
                              hipStream_t stream){
  const float* x     = (const float*)d_in[0];
  const int*   lens  = (const int*)  d_in[1];
  const float* h0    = (const float*)d_in[2];
  const float* c0    = (const float*)d_in[3];
  const float* W_is0 = (const float*)d_in[4];
  const float* b_is0 = (const float*)d_in[5];
  const float* W_is1 = (const float*)d_in[6];
  const float* b_is1 = (const float*)d_in[7];
  const float* W_ih  = (const float*)d_in[8];
  const float* W_hh  = (const float*)d_in[9];
  const float* b_ih  = (const float*)d_in[10];
  const float* b_hh  = (const float*)d_in[11];
  const float* W_o   = (const float*)d_in[12];
  const float* b_o   = (const float*)d_in[13];
  float* out = (float*)d_out;

  char* ws = (char*)d_ws;   // needs ~74 MB
  uint16_t* G      = (uint16_t*)(ws + OFF_G);
  uint16_t* temb   = (uint16_t*)(ws + OFF_TEMB);
  uint16_t* h_hist = (uint16_t*)(ws + OFF_HH);
  uint16_t* whh_b  = (uint16_t*)(ws + OFF_WHH);
  uint16_t* wmid_b = (uint16_t*)(ws + OFF_WMID);
  float* wc0  = (float*)(ws + OFF_WC0);
  float* wc1  = (float*)(ws + OFF_WC1);
  float* bc   = (float*)(ws + OFF_BC);
  float* hfin = (float*)(ws + OFF_HFIN);

  hipLaunchKernelGGL(prep1, dim3(2048), dim3(256), 0, stream,
                     W_ih, W_hh, W_is0, b_is0, W_is1, b_is1, b_ih, b_hh,
                     whh_b, wmid_b, wc0, wc1, bc);
  hipLaunchKernelGGL(prep2, dim3(16512), dim3(256), 0, stream, h0, h_hist);
  hipLaunchKernelGGL(tembk, dim3(8192), dim3(256), 0, stream, x, temb);
  hipLaunchKernelGGL(gemmB, dim3(64, 16), dim3(256), 0, stream, temb, wmid_b, G);
  hipLaunchKernelGGL(lstmk, dim3(128), dim3(256), 0, stream,
                     x, c0, lens, whh_b, G, wc0, wc1, bc, h_hist, hfin);
  hipLaunchKernelGGL(outk, dim3(64), dim3(256), 0, stream, hfin, W_o, b_o, out);
}

// Round 12
// 569.082 us; speedup vs baseline: 1.5391x; 1.0374x over previous
//
#include <hip/hip_runtime.h>
#include <hip/hip_bf16.h>
#include <stdint.h>

// Problem: B=64, T=128, F=16, H=512, S=2.  All inputs fp32, lengths int32, out fp32 [64][14].
//
// History: R2 1338us -> R3 relaxed poll 831 -> R5 poll-on-data 656 -> R6 coalesced poll 612
// -> R9 dense transactions (lstmk 400, MALL-RT floor) -> R11 gemmB m97-staging, total 590.
// Failed: R4 release-flags, R7 poll backoff, R8 64x512, R10 XCD-local sc0 fast path.
//
// R12: HIDE gemmB UNDER THE RECURRENCE (single fused kernel):
//   - G relaid TIME-MAJOR: row' = ntm*64 + b. An m-tile (128 rows) = 2 ntm x all 64 b, so
//     lstm step t needs exactly m-tile (qidx>>2) -> per-tile ready flags become useful.
//   - fused kernel: blocks 0..127 = lstm role (R9-exact + flag check every 4th step +
//     time-major G rows); blocks 128..1151 = gemm role (R11 gemmB, time-major tiles,
//     agent-scope/MALL write-through epilogue, __syncthreads drain, one RELEASE flag per
//     (mtile,ntile)). m-tile order interleaved (32,0,33,1,..) so both segments unblock fast.
//     No deadlock: lstm blocks (35KB LDS, ~116 VGPR) always leave room for gemm blocks.
//   - prepAll: prep1 || tembk || h level-0+gflag zero || vectorized sentinel fill, one kernel.
//
// Reshape quirk (faithful to torch): segment s', step t' uses source timestep n_t=(s'*128+t')>>1
// and embedding branch n_s=(s'*128+t')&1.

typedef __attribute__((ext_vector_type(8))) short bf16x8_t;
typedef __attribute__((ext_vector_type(4))) float f32x4_t;

#define SENT 0xAAAAAAAAu

// ---------------- workspace layout (bytes) ----------------
#define OFF_G      0u                      // bf16 [8192][2048] time-major rows  33,554,432
#define OFF_TEMB   33554432u               // bf16 [8192][1024]   16,777,216
#define OFF_HH     50331648u               // bf16 [129][8rr][16cg][16row][32u] 16,908,288
#define OFF_WHH    67239936u               // bf16 [2048][512]     2,097,152
#define OFF_WMID   69337088u               // bf16 [2048][1024]    4,194,304
#define OFF_WC0    73531392u               // f32  [2048][8]          65,536
#define OFF_WC1    73596928u               // f32  [2048][8] (6 used) 65,536
#define OFF_BC     73662464u               // f32  [2][2048]          16,384
#define OFF_HFIN   73678848u               // f32  [64][1024]        262,144
#define OFF_GFLAG  73940992u               // u32  [64][16]             4,096
// total ~74 MB

__device__ __forceinline__ float bf2f(uint16_t u){
  union { uint32_t i; float f; } v; v.i = ((uint32_t)u) << 16; return v.f;
}
__device__ __forceinline__ uint16_t f2b(float f){
  union { float f; uint32_t i; } v; v.f = f;
  uint32_t r = v.i + 0x7fffu + ((v.i >> 16) & 1u);  // RNE
  return (uint16_t)(r >> 16);
}
__device__ __forceinline__ float sigm(float x){ return 1.0f/(1.0f + __expf(-x)); }
__device__ __forceinline__ float tanh_(float x){
  float xc = fminf(fmaxf(x, -15.f), 15.f);
  float t = __expf(2.f*xc);
  return (t - 1.f)/(t + 1.f);
}
__device__ __forceinline__ void gl_lds16(const void* g, void* l){
  __builtin_amdgcn_global_load_lds(
      (const __attribute__((address_space(1))) void*)g,
      (__attribute__((address_space(3))) void*)l, 16, 0, 0);
}

// ---------------- prepAll: prep1(2048) | tembk(8192) | lvl0+gflag(128) | sentinel(2048) ------
__global__ void prepAll(const float* __restrict__ x,
                        const float* __restrict__ W_ih, const float* __restrict__ W_hh,
                        const float* __restrict__ W_is0, const float* __restrict__ b_is0,
                        const float* __restrict__ W_is1, const float* __restrict__ b_is1,
                        const float* __restrict__ b_ih, const float* __restrict__ b_hh,
                        const float* __restrict__ h0,
                        uint16_t* __restrict__ whh_b, uint16_t* __restrict__ wmid_b,
                        float* __restrict__ wc0, float* __restrict__ wc1,
                        float* __restrict__ bc,
                        uint16_t* __restrict__ temb, uint16_t* __restrict__ h_hist,
                        uint32_t* __restrict__ gflag){
  const int bid = blockIdx.x, tid = threadIdx.x;
  if (bid < 2048){
    // ---- prep1 role: weight folding + bf16 casts ----
    const int n = bid;
    __shared__ float wrow[512];
    __shared__ float red[16][17];
    wrow[tid]       = W_ih[(size_t)n*1536 + tid];
    wrow[tid + 256] = W_ih[(size_t)n*1536 + 256 + tid];
    for (int j = tid; j < 1024; j += 256)
      wmid_b[(size_t)n*1024 + j] = f2b(W_ih[(size_t)n*1536 + 512 + j]);
    for (int k = tid; k < 512; k += 256)
      whh_b[(size_t)n*512 + k] = f2b(W_hh[(size_t)n*512 + k]);
    __syncthreads();
    {
      const int d = tid >> 4, jp = tid & 15;
      float s = 0.f;
      const int kk0 = jp*32;
      if (d < 8){
        for (int k = kk0; k < kk0 + 32; ++k) s += wrow[k]*W_is0[k*8 + d];
      } else if (d < 14){
        int c = d - 8;
        for (int k = kk0; k < kk0 + 32; ++k) s += wrow[k]*W_is1[k*6 + c];
      } else if (d == 14){
        for (int k = kk0; k < kk0 + 32; ++k) s += wrow[k]*b_is0[k];
      } else {
        for (int k = kk0; k < kk0 + 32; ++k) s += wrow[k]*b_is1[k];
      }
      red[d][jp] = s;
    }
    __syncthreads();
    if (tid < 16){
      float tot = 0.f;
      #pragma unroll
      for (int i = 0; i < 16; ++i) tot += red[tid][i];
      if (tid < 8)        wc0[n*8 + tid] = tot;
      else if (tid < 14)  wc1[n*8 + (tid - 8)] = tot;
      else if (tid == 14) bc[n]        = b_ih[n] + b_hh[n] + tot;
      else                bc[2048 + n] = b_ih[n] + b_hh[n] + tot;
    } else if (tid == 16){
      wc1[n*8 + 6] = 0.f; wc1[n*8 + 7] = 0.f;
    }
  } else if (bid < 10240){
    // ---- tembk role ----
    const int rid = bid - 2048;       // (b*128 + t)
    const int k = tid;
    float x0 = x[(size_t)rid*16 + 0], x1 = x[(size_t)rid*16 + 1];
    float f = __expf((float)k * (-9.210340371976184f/256.f));
    float a0 = x0*f, a1 = x1*f;
    size_t base = (size_t)rid*1024;
    temb[base + k]        = f2b(__cosf(a0));
    temb[base + 256 + k]  = f2b(__sinf(a0));
    temb[base + 512 + k]  = f2b(__cosf(a1));
    temb[base + 768 + k]  = f2b(__sinf(a1));
  } else if (bid < 10368){
    // ---- level-0 h + gflag zero ----
    int i = (bid - 10240)*256 + tid;   // 0..32767
    uint32_t* hh = (uint32_t*)h_hist;
    int e    = i*2;
    int rrcg = e >> 9;
    int rr   = rrcg >> 4, cg = rrcg & 15;
    int rm   = e & 511;
    int row  = rm >> 5, u = rm & 31;
    int b    = (rr*16 + row) & 63;
    int unit = cg*32 + u;
    uint32_t lo = f2b(h0[(size_t)b*512 + unit]);
    uint32_t hi = f2b(h0[(size_t)b*512 + unit + 1]);
    uint32_t wd = lo | (hi << 16);
    if (wd == SENT) wd ^= 1u;
    hh[i] = wd;
    if (i < 1024) gflag[i] = 0u;
  } else {
    // ---- sentinel fill role: words [32768, 4227072), 8 per thread via 2x uint4 ----
    uint32_t* hh = (uint32_t*)h_hist;
    size_t w0 = 32768u + ((size_t)(bid - 10368)*256 + tid)*8;
    uint4 s4 = make_uint4(SENT, SENT, SENT, SENT);
    *(uint4*)&hh[w0]     = s4;
    *(uint4*)&hh[w0 + 4] = s4;
  }
}

// ---------------- fused: lstm role (bid 0..127) + gemm role (bid 128..1151) ----------------
// lstm: 8 row-groups x 16 col-groups, blockIdx = g*8 + rr (R9-exact protocol).
// h_hist level layout: [rr][cg16][row16][u32], 1KB/region. G time-major: row' = ntm*64 + b.
__launch_bounds__(256)
__global__ void fusedk(const float* __restrict__ x, const float* __restrict__ c0,
                       const int* __restrict__ lengths,
                       const uint16_t* __restrict__ whh_b, const uint16_t* __restrict__ temb,
                       const uint16_t* __restrict__ wmid,
                       const float* __restrict__ wc0, const float* __restrict__ wc1,
                       const float* __restrict__ bc,
                       uint16_t* __restrict__ G, uint16_t* __restrict__ h_hist,
                       uint32_t* __restrict__ gflag, float* __restrict__ hfin){
  __shared__ __align__(16) uint16_t smem_u[17664];   // lstm: h_l[2][16][552]; gemm: 32KB tiles
  const int tid = threadIdx.x;
  const int bid = blockIdx.x;
  const int w = tid >> 6, lane = tid & 63;
  const int q = lane >> 4, ln = lane & 15;

  if (bid >= 128){
    // ================= gemm role =================
    const int gb = bid - 128;
    const int idx = gb >> 4;
    const int mt = (idx & 1) ? (idx >> 1) : (32 + (idx >> 1));  // seg1 tiles first
    const int n0 = (gb & 15)*128;
    uint16_t* Al = smem_u;
    uint16_t* Bl = smem_u + 8192;
    const int wm = w >> 1, wn = w & 1;
    const int srow_l = lane >> 3, scol = (lane & 7)*8;

    f32x4_t acc[4][4];
    #pragma unroll
    for (int a = 0; a < 4; ++a)
      #pragma unroll
      for (int b2 = 0; b2 < 4; ++b2) acc[a][b2] = (f32x4_t){0.f,0.f,0.f,0.f};

    for (int kb = 0; kb < 16; ++kb){
      #pragma unroll
      for (int i = 0; i < 4; ++i){
        int row0 = w*32 + i*8;
        int lrow = row0 + srow_l;
        int bA = lrow & 63, ntmA = mt*2 + (lrow >> 6);
        gl_lds16(temb + (size_t)(bA*128 + ntmA)*1024 + kb*64 + scol, &Al[row0*64]);
        gl_lds16(wmid + (size_t)(n0 + lrow)*1024 + kb*64 + scol, &Bl[row0*64]);
      }
      __syncthreads();
      #pragma unroll
      for (int kc = 0; kc < 2; ++kc){
        bf16x8_t af[4], bf[4];
        #pragma unroll
        for (int mt_i = 0; mt_i < 4; ++mt_i)
          af[mt_i] = *(const bf16x8_t*)&Al[(wm*64 + mt_i*16 + ln)*64 + kc*32 + q*8];
        #pragma unroll
        for (int nt = 0; nt < 4; ++nt)
          bf[nt] = *(const bf16x8_t*)&Bl[(wn*64 + nt*16 + ln)*64 + kc*32 + q*8];
        #pragma unroll
        for (int mt_i = 0; mt_i < 4; ++mt_i)
          #pragma unroll
          for (int nt = 0; nt < 4; ++nt)
            acc[mt_i][nt] = __builtin_amdgcn_mfma_f32_16x16x32_bf16(af[mt_i], bf[nt], acc[mt_i][nt], 0, 0, 0);
      }
      __syncthreads();
    }
    // C bounce (C/D: col=lane&15, row=quad*4+reg — m89-verified)
    #pragma unroll
    for (int mt_i = 0; mt_i < 4; ++mt_i)
      #pragma unroll
      for (int nt = 0; nt < 4; ++nt)
        #pragma unroll
        for (int r = 0; r < 4; ++r){
          int Mr = wm*64 + mt_i*16 + q*4 + r;
          int Nc = wn*64 + nt*16 + ln;
          smem_u[Mr*128 + Nc] = f2b(acc[mt_i][nt][r]);
        }
    __syncthreads();
    // epilogue: agent-scope (MALL write-through) stores, 128B/thread contiguous
    {
      const int erow = tid >> 1, eh = tid & 1;
      const unsigned long long* lsrc = (const unsigned long long*)&smem_u[erow*128 + eh*64];
      unsigned long long* gdst = (unsigned long long*)
          (G + (size_t)(mt*128 + erow)*2048 + n0 + eh*64);
      #pragma unroll
      for (int i2 = 0; i2 < 16; ++i2)
        __hip_atomic_store(&gdst[i2], lsrc[i2], __ATOMIC_RELAXED, __HIP_MEMORY_SCOPE_AGENT);
    }
    __syncthreads();   // each wave drains vmcnt(0) before barrier -> all stores in MALL
    if (tid == 0)
      __hip_atomic_store(&gflag[mt*16 + (gb & 15)], 1u,
                         __ATOMIC_RELEASE, __HIP_MEMORY_SCOPE_AGENT);
    return;
  }

  // ================= lstm role (R9-exact + time-major G + gflag gating) =================
  #define HL(b,r,c) smem_u[(((b)*16 + (r))*552) + (c)]
  const int rr = bid & 7;
  const int g  = bid >> 3;
  const int k0 = g*32;
  const int sp = rr >> 2;
  const int u8 = ln & 7, gh = ln >> 3;
  const int unit = k0 + w*8 + u8;
  const int gl0 = gh*512 + unit;
  const int gl1 = (2 + gh)*512 + unit;
  const int LVL = 65536;

  bf16x8_t barr0[16], barr1[16];
  #pragma unroll
  for (int kc = 0; kc < 16; ++kc){
    barr0[kc] = *(const bf16x8_t*)(whh_b + (size_t)gl0*512 + kc*32 + q*8);
    barr1[kc] = *(const bf16x8_t*)(whh_b + (size_t)gl1*512 + kc*32 + q*8);
  }
  bf16x8_t e0f[2], e1f[2];
  #pragma unroll
  for (int nsI = 0; nsI < 2; ++nsI){
    bf16x8_t v0 = {0,0,0,0,0,0,0,0}, v1 = {0,0,0,0,0,0,0,0};
    if (q == 0){
      const float* wcs = nsI ? wc1 : wc0;
      #pragma unroll
      for (int jj = 0; jj < 8; ++jj){
        ((uint16_t*)&v0)[jj] = f2b(wcs[gl0*8 + jj]);
        ((uint16_t*)&v1)[jj] = f2b(wcs[gl1*8 + jj]);
      }
    }
    e0f[nsI] = v0; e1f[nsI] = v1;
  }
  float bc0v[2] = { bc[gl0], bc[2048 + gl0] };
  float bc1v[2] = { bc[gl1], bc[2048 + gl1] };

  int   bmr[4], lenr[4];
  float cst[4];
  #pragma unroll
  for (int r = 0; r < 4; ++r){
    int row = rr*16 + q*4 + r;
    bmr[r]  = row & 63;
    lenr[r] = lengths[bmr[r]];
    cst[r]  = c0[(size_t)bmr[r]*512 + unit];
  }

  const int prow = lane >> 2;
  const int pcol = (lane & 3)*8;
  const int xm = tid >> 3, xc = tid & 7;
  const int xb = (rr*16 + xm) & 63;
  const size_t stb = ((size_t)rr*8192 + g*512);

  for (int idx2 = tid; idx2 < 2*16*32; idx2 += 256)
    HL(idx2 >> 9, (idx2 >> 5) & 15, 520 + (idx2 & 31)) = 0;

  for (int t = 0; t < 128; ++t){
    const int qidx = sp*128 + t;
    const int ntm = qidx >> 1;
    const int ns  = qidx & 1;
    const int buf = t & 1;

    // --- gate on G m-tile readiness (once per 4 steps; broadcast-address poll) ---
    if ((t & 3) == 0){
      const int mt = qidx >> 2;
      const uint32_t* gf = gflag + mt*16 + (g >> 2);
      while (true){
        bool ok = true;
        #pragma unroll
        for (int j = 0; j < 4; ++j){
          uint32_t v = __hip_atomic_load(&gf[j*4], __ATOMIC_RELAXED, __HIP_MEMORY_SCOPE_AGENT);
          ok &= (v != 0u);
        }
        if (ok) break;
        __builtin_amdgcn_s_sleep(1);
      }
    }

    // --- early independent loads: G slice (time-major rows, cached) + xf source ---
    uint16_t g0r[4], g1r[4];
    #pragma unroll
    for (int r = 0; r < 4; ++r){
      size_t grow = (size_t)(ntm*64 + bmr[r])*2048;
      g0r[r] = G[grow + gl0];
      g1r[r] = G[grow + gl1];
    }
    float xv = 0.f;
    if (tid < 128){
      if (ns == 0)      xv = x[(size_t)(xb*128 + ntm)*16 + 2 + xc];
      else if (xc < 6)  xv = x[(size_t)(xb*128 + ntm)*16 + 10 + xc];
    }

    // --- hot poll-on-data, lane-dense (R9) ---
    {
      const unsigned long long* lvl = (const unsigned long long*)h_hist
                                      + (((size_t)t*LVL + (size_t)rr*8192) >> 2);
      unsigned long long hv[4][2];
      while (true){
        bool ok = true;
        #pragma unroll
        for (int i = 0; i < 4; ++i){
          const unsigned long long* p = lvl + ((size_t)(w*4 + i)*128 + prow*8 + (pcol >> 2));
          hv[i][0] = __hip_atomic_load(&p[0], __ATOMIC_RELAXED, __HIP_MEMORY_SCOPE_AGENT);
          hv[i][1] = __hip_atomic_load(&p[1], __ATOMIC_RELAXED, __HIP_MEMORY_SCOPE_AGENT);
          ok &= ((uint32_t)hv[i][0] != SENT) & ((uint32_t)(hv[i][0] >> 32) != SENT)
              & ((uint32_t)hv[i][1] != SENT) & ((uint32_t)(hv[i][1] >> 32) != SENT);
        }
        if (__all(ok)) break;
        __builtin_amdgcn_s_sleep(1);
      }
      #pragma unroll
      for (int i = 0; i < 4; ++i){
        int reg = w*4 + i;
        *(unsigned long long*)&HL(buf, prow, reg*32 + pcol)     = hv[i][0];
        *(unsigned long long*)&HL(buf, prow, reg*32 + pcol + 4) = hv[i][1];
      }
    }
    if (tid < 128) HL(buf, xm, 512 + xc) = f2b(xv);
    __syncthreads();

    // --- gates = G + bias + [h|xf] @ [Whh|Wc]^T ---
    f32x4_t acc0, acc1;
    {
      float b0 = ns ? bc0v[1] : bc0v[0];
      float b1 = ns ? bc1v[1] : bc1v[0];
      #pragma unroll
      for (int r = 0; r < 4; ++r){ acc0[r] = bf2f(g0r[r]) + b0; acc1[r] = bf2f(g1r[r]) + b1; }
    }
    #pragma unroll
    for (int kc = 0; kc < 16; ++kc){
      bf16x8_t a = *(const bf16x8_t*)&HL(buf, ln, kc*32 + q*8);
      acc0 = __builtin_amdgcn_mfma_f32_16x16x32_bf16(a, barr0[kc], acc0, 0, 0, 0);
      acc1 = __builtin_amdgcn_mfma_f32_16x16x32_bf16(a, barr1[kc], acc1, 0, 0, 0);
    }
    {
      bf16x8_t a = *(const bf16x8_t*)&HL(buf, ln, 512 + q*8);
      acc0 = __builtin_amdgcn_mfma_f32_16x16x32_bf16(a, ns ? e0f[1] : e0f[0], acc0, 0, 0, 0);
      acc1 = __builtin_amdgcn_mfma_f32_16x16x32_bf16(a, ns ? e1f[1] : e1f[0], acc1, 0, 0, 0);
    }

    float pf[4], po[4];
    #pragma unroll
    for (int r = 0; r < 4; ++r){
      pf[r] = __shfl_xor(acc0[r], 8);
      po[r] = __shfl_xor(acc1[r], 8);
    }
    if (ln < 8){
      uint32_t hb[4]; float hF[4];
      #pragma unroll
      for (int r = 0; r < 4; ++r){
        float ig = acc0[r], fg = pf[r], gg = acc1[r], og = po[r];
        cst[r] = sigm(fg)*cst[r] + sigm(ig)*tanh_(gg);
        float h = sigm(og)*tanh_(cst[r]);
        hF[r] = h; hb[r] = (uint32_t)f2b(h);
      }
      #pragma unroll
      for (int r = 0; r < 4; ++r){
        uint32_t ph = (uint32_t)__shfl_xor((int)hb[r], 1);
        uint32_t packed = hb[r] | (ph << 16);
        if (packed == SENT) packed ^= 1u;
        uint32_t hi = (uint32_t)__shfl_xor((int)packed, 2);
        if ((ln & 3) == 0){
          unsigned long long v = (unsigned long long)packed | ((unsigned long long)hi << 32);
          unsigned long long* hp = (unsigned long long*)h_hist
              + (((size_t)(t+1)*LVL + stb + (size_t)(q*4 + r)*32 + w*8 + u8) >> 2);
          __hip_atomic_store(hp, v, __ATOMIC_RELAXED, __HIP_MEMORY_SCOPE_AGENT);
        }
        if (t == lenr[r] - 1)
          hfin[(size_t)bmr[r]*1024 + sp*512 + unit] = hF[r];
      }
    }
  }
  #undef HL
}

// ---------------- outk: out = sigmoid(hfin @ W_o^T + b_o) ----------------
__global__ void outk(const float* __restrict__ hfin, const float* __restrict__ W_o,
                     const float* __restrict__ b_o, float* __restrict__ out){
  __shared__ float hl[1024];
  __shared__ float red[16][17];
  const int b = blockIdx.x, tid = threadIdx.x;
  #pragma unroll
  for (int i = 0; i < 4; ++i) hl[tid + i*256] = hfin[(size_t)b*1024 + tid + i*256];
  __syncthreads();
  const int o = tid >> 4, j0 = tid & 15;
  float s = 0.f;
  if (o < 14){
    for (int j = j0; j < 1024; j += 16) s += hl[j]*W_o[(size_t)o*1024 + j];
  }
  red[o][j0] = s;
  __syncthreads();
  if (tid < 14){
    float tot = b_o[tid];
    #pragma unroll
    for (int i = 0; i < 16; ++i) tot += red[tid][i];
    out[b*14 + tid] = 1.0f/(1.0f + __expf(-tot));
  }
}

extern "C" void kernel_launch(void* const* d_in, const int* in_sizes, int n_in,
                              void* d_out, int out_size, void* d_ws, size_t ws_size,
                              hipStream_t stream){
  const float* x     = (const float*)d_in[0];
  const int*   lens  = (const int*)  d_in[1];
  const float* h0    = (const float*)d_in[2];
  const float* c0    = (const float*)d_in[3];
  const float* W_is0 = (const float*)d_in[4];
  const float* b_is0 = (const float*)d_in[5];
  const float* W_is1 = (const float*)d_in[6];
  const float* b_is1 = (const float*)d_in[7];
  const float* W_ih  = (const float*)d_in[8];
  const float* W_hh  = (const float*)d_in[9];
  const float* b_ih  = (const float*)d_in[10];
  const float* b_hh  = (const float*)d_in[11];
  const float* W_o   = (const float*)d_in[12];
  const float* b_o   = (const float*)d_in[13];
  float* out = (float*)d_out;

  char* ws = (char*)d_ws;   // needs ~74 MB
  uint16_t* G      = (uint16_t*)(ws + OFF_G);
  uint16_t* temb   = (uint16_t*)(ws + OFF_TEMB);
  uint16_t* h_hist = (uint16_t*)(ws + OFF_HH);
  uint16_t* whh_b  = (uint16_t*)(ws + OFF_WHH);
  uint16_t* wmid_b = (uint16_t*)(ws + OFF_WMID);
  float* wc0  = (float*)(ws + OFF_WC0);
  float* wc1  = (float*)(ws + OFF_WC1);
  float* bc   = (float*)(ws + OFF_BC);
  float* hfin = (float*)(ws + OFF_HFIN);
  uint32_t* gflag = (uint32_t*)(ws + OFF_GFLAG);

  hipLaunchKernelGGL(prepAll, dim3(12416), dim3(256), 0, stream,
                     x, W_ih, W_hh, W_is0, b_is0, W_is1, b_is1, b_ih, b_hh, h0,
                     whh_b, wmid_b, wc0, wc1, bc, temb, h_hist, gflag);
  hipLaunchKernelGGL(fusedk, dim3(1152), dim3(256), 0, stream,
                     x, c0, lens, whh_b, temb, wmid_b, wc0, wc1, bc,
                     G, h_hist, gflag, hfin);
  hipLaunchKernelGGL(outk, dim3(64), dim3(256), 0, stream, hfin, W_o, b_o, out);
}